// Round 7
// baseline (2297.565 us; speedup 1.0000x reference)
//
#include <hip/hip_runtime.h>
#include <math.h>

#define B 64
#define N 196
#define E 2048
#define D 512
#define AA 512
#define EM 512
#define V 10000
#define TSTEPS 20
#define XC 3072          // xcat: [inp(512) | awe(2048) | h(512)] contiguous
#define HOFF 2560        // h slot offset in xcat
#define AGW 2560         // ag row: [att2(512) | gate(2048)]
#define AGS 4            // split-K slices for att2|gate (K=512 -> 128 each)
#define ZS1 8            // split-K slices for W_ih (K=2560 -> 320 each)
#define ZS2 4            // split-K slices for W_hh (K=512 -> 128 each)
#define PS 2             // split-K slices for preds (K=512 -> 256 each)
#define ATT1_ELEMS ((size_t)B * N * AA)   // 6422528

__device__ __forceinline__ float sigmoidf_(float x) { return 1.0f / (1.0f + expf(-x)); }

__device__ __forceinline__ float4 ldg4_guard(const float* __restrict__ wp, int n, int Nn) {
    if (n + 3 < Nn) return *(const float4*)&wp[n];
    float4 bv;
    bv.x = (n     < Nn) ? wp[n]     : 0.f;
    bv.y = (n + 1 < Nn) ? wp[n + 1] : 0.f;
    bv.z = (n + 2 < Nn) ? wp[n + 2] : 0.f;
    bv.w = (n + 3 < Nn) ? wp[n + 3] : 0.f;
    return bv;
}

// ---------------- mean over N ----------------
__global__ __launch_bounds__(256) void k_mean(const float* __restrict__ feat,
                                              float* __restrict__ mean_enc) {
    int i = blockIdx.x * 256 + threadIdx.x;
    int b = i >> 11, e = i & (E - 1);
    const float* p = feat + (size_t)b * N * E + e;
    float s = 0.f;
    for (int n = 0; n < N; ++n) s += p[(size_t)n * E];
    mean_enc[i] = s * (1.0f / (float)N);
}

// ---------------- h,c init; h written into xcat h-slot ----------------
__global__ __launch_bounds__(256) void k_init_hc(const float* __restrict__ me,
                                                 const float* __restrict__ Wh, const float* __restrict__ bh,
                                                 const float* __restrict__ Wc, const float* __restrict__ bc,
                                                 float* __restrict__ xcat, float* __restrict__ c) {
    int i = blockIdx.x * 256 + threadIdx.x;
    int b = i >> 9, d = i & (D - 1);
    const float* m = me + (size_t)b * E;
    float ha = bh[d], ca = bc[d];
    for (int e = 0; e < E; ++e) {
        float mv = m[e];
        ha += mv * Wh[(size_t)e * D + d];
        ca += mv * Wc[(size_t)e * D + d];
    }
    xcat[(size_t)b * XC + HOFF + d] = ha;
    c[i] = ca;
}

// ---------------- inp = embedding[1] into xcat ----------------
__global__ __launch_bounds__(256) void k_init_inp(const float* __restrict__ emb,
                                                  float* __restrict__ xcat) {
    int i = blockIdx.x * 256 + threadIdx.x;   // 32768
    int b = i >> 9, k = i & (EM - 1);
    xcat[(size_t)b * XC + k] = emb[EM + k];
}

// ---------------- att1 = enc @ W_enc_att : 256x128 tile, 16x8 micro, split-K 2 ----------------
// 0.75 B/FMA LDS demand (vs 1.0 at 8x8) -> VALU ceiling ~88% vs 66%.
// A staged [k][m] (scalar transposed writes, 1 row/thread); A-frag reads are broadcasts.
// grid (196, 2), bijective XCD chunking (q=24, r=4). ~190 VGPR, 2 waves/SIMD, all resident.
__global__ __launch_bounds__(256) void k_gemm_att1(const float* __restrict__ Am,
                                                   const float* __restrict__ Bm,
                                                   float* __restrict__ Cp) {
    __shared__ float As[16][256];   // [k][m]
    __shared__ float Bs[16][128];   // [k][n]
    int bid = blockIdx.x;           // 196 = 49 row-tiles x 4 col-tiles
    int xcd = bid & 7, idx = bid >> 3;
    int wg = (xcd < 4 ? xcd * 25 : 100 + (xcd - 4) * 24) + idx;   // bijective (m204)
    int row0 = (wg >> 2) * 256, col0 = (wg & 3) * 128;
    int kbeg = blockIdx.y * (E / 2);
    float* Cm = Cp + (size_t)blockIdx.y * ATT1_ELEMS;
    int t = threadIdx.x;
    int ty = t >> 4, tx = t & 15;
    const float* aptr = Am + (size_t)(row0 + t) * E + kbeg;                 // 1 row/thread
    const float* bptr = Bm + (size_t)(kbeg + (t >> 4)) * AA + col0 + (t & 15) * 8;
    float4 pa0 = *(const float4*)(aptr);
    float4 pa1 = *(const float4*)(aptr + 4);
    float4 pa2 = *(const float4*)(aptr + 8);
    float4 pa3 = *(const float4*)(aptr + 12);
    float4 pb0 = *(const float4*)(bptr);
    float4 pb1 = *(const float4*)(bptr + 4);
    float acc[16][8] = {};
    for (int k0 = 0; k0 < E / 2; k0 += 16) {
        // stage regs -> LDS
        As[ 0][t] = pa0.x; As[ 1][t] = pa0.y; As[ 2][t] = pa0.z; As[ 3][t] = pa0.w;
        As[ 4][t] = pa1.x; As[ 5][t] = pa1.y; As[ 6][t] = pa1.z; As[ 7][t] = pa1.w;
        As[ 8][t] = pa2.x; As[ 9][t] = pa2.y; As[10][t] = pa2.z; As[11][t] = pa2.w;
        As[12][t] = pa3.x; As[13][t] = pa3.y; As[14][t] = pa3.z; As[15][t] = pa3.w;
        *(float4*)&Bs[t >> 4][(t & 15) * 8]     = pb0;
        *(float4*)&Bs[t >> 4][(t & 15) * 8 + 4] = pb1;
        __syncthreads();
        if (k0 + 16 < E / 2) {      // prefetch next k-tile (in flight during compute)
            const float* ap = aptr + k0 + 16;
            const float* bp = bptr + (size_t)(k0 + 16) * AA;
            pa0 = *(const float4*)(ap);
            pa1 = *(const float4*)(ap + 4);
            pa2 = *(const float4*)(ap + 8);
            pa3 = *(const float4*)(ap + 12);
            pb0 = *(const float4*)(bp);
            pb1 = *(const float4*)(bp + 4);
        }
#pragma unroll
        for (int kk = 0; kk < 16; ++kk) {
            float af[16], bf[8];
            *(float4*)&af[0]  = *(const float4*)&As[kk][ty * 16];
            *(float4*)&af[4]  = *(const float4*)&As[kk][ty * 16 + 4];
            *(float4*)&af[8]  = *(const float4*)&As[kk][ty * 16 + 8];
            *(float4*)&af[12] = *(const float4*)&As[kk][ty * 16 + 12];
            *(float4*)&bf[0]  = *(const float4*)&Bs[kk][tx * 8];
            *(float4*)&bf[4]  = *(const float4*)&Bs[kk][tx * 8 + 4];
#pragma unroll
            for (int i = 0; i < 16; ++i)
#pragma unroll
                for (int j = 0; j < 8; ++j)
                    acc[i][j] += af[i] * bf[j];
        }
        __syncthreads();
    }
#pragma unroll
    for (int i = 0; i < 16; ++i) {
        float* cp = &Cm[(size_t)(row0 + ty * 16 + i) * AA + col0 + tx * 8];
        float4 lo, hi;
        lo.x = acc[i][0]; lo.y = acc[i][1]; lo.z = acc[i][2]; lo.w = acc[i][3];
        hi.x = acc[i][4]; hi.y = acc[i][5]; hi.z = acc[i][6]; hi.w = acc[i][7];
        *(float4*)cp       = lo;
        *(float4*)(cp + 4) = hi;
    }
}

// ---------------- att1 += att1 slice1 (in place, deterministic) ----------------
__global__ __launch_bounds__(256) void k_att1_red(float* __restrict__ att1) {
    size_t i = ((size_t)blockIdx.x * 256 + threadIdx.x) * 4;
    float4 a = *(float4*)&att1[i];
    float4 b = *(const float4*)&att1[i + ATT1_ELEMS];
    a.x += b.x; a.y += b.y; a.z += b.z; a.w += b.w;
    *(float4*)&att1[i] = a;
}

// ---------------- att2|gate split-K: agp[sl][b][2560] (register-prefetched) ----------------
__global__ __launch_bounds__(256) void k_ag(const float* __restrict__ xcat,
                                            const float* __restrict__ Wda,
                                            const float* __restrict__ Wfb,
                                            const float* __restrict__ bfb,
                                            float* __restrict__ agp) {
    __shared__ float As[16][68];
    __shared__ float Bs[16][64];
    int tile = blockIdx.x, slice = blockIdx.y;
    const float* W; const float* bias = nullptr; int ldw, n0, co;
    if (tile < 8) { W = Wda; ldw = AA; n0 = tile * 64;       co = n0; }
    else          { W = Wfb; ldw = E;  n0 = (tile - 8) * 64; co = AA + n0;
                    if (slice == 0) bias = bfb; }
    float* ag = agp + (size_t)slice * B * AGW;
    int kbeg = slice * (D / AGS), kend = kbeg + D / AGS;
    const float* A = xcat + HOFF;
    int t = threadIdx.x;
    int tx = t & 15, ty = t >> 4;
    int arow = t >> 2, ak4 = (t & 3) * 4;
    int bk = t >> 4, bc4 = (t & 15) * 4;
    float4 pav = *(const float4*)&A[(size_t)arow * XC + kbeg + ak4];
    float4 pbv = *(const float4*)&W[(size_t)(kbeg + bk) * ldw + n0 + bc4];
    float acc[4][4] = {};
    for (int k0 = kbeg; k0 < kend; k0 += 16) {
        As[ak4 + 0][arow] = pav.x; As[ak4 + 1][arow] = pav.y;
        As[ak4 + 2][arow] = pav.z; As[ak4 + 3][arow] = pav.w;
        *(float4*)&Bs[bk][bc4] = pbv;
        __syncthreads();
        if (k0 + 16 < kend) {
            pav = *(const float4*)&A[(size_t)arow * XC + k0 + 16 + ak4];
            pbv = *(const float4*)&W[(size_t)(k0 + 16 + bk) * ldw + n0 + bc4];
        }
#pragma unroll
        for (int kk = 0; kk < 16; ++kk) {
            float4 a4 = *(const float4*)&As[kk][ty * 4];
            float4 b4 = *(const float4*)&Bs[kk][tx * 4];
            acc[0][0] += a4.x * b4.x; acc[0][1] += a4.x * b4.y; acc[0][2] += a4.x * b4.z; acc[0][3] += a4.x * b4.w;
            acc[1][0] += a4.y * b4.x; acc[1][1] += a4.y * b4.y; acc[1][2] += a4.y * b4.z; acc[1][3] += a4.y * b4.w;
            acc[2][0] += a4.z * b4.x; acc[2][1] += a4.z * b4.y; acc[2][2] += a4.z * b4.z; acc[2][3] += a4.z * b4.w;
            acc[3][0] += a4.w * b4.x; acc[3][1] += a4.w * b4.y; acc[3][2] += a4.w * b4.z; acc[3][3] += a4.w * b4.w;
        }
        __syncthreads();
    }
#pragma unroll
    for (int i = 0; i < 4; ++i) {
        int row = ty * 4 + i;
#pragma unroll
        for (int j = 0; j < 4; ++j) {
            float v = acc[i][j];
            if (bias) v += bias[n0 + tx * 4 + j];
            ag[(size_t)row * AGW + co + tx * 4 + j] = v;
        }
    }
}

// ---------------- scores: wave per (b,n) row, float4; sums AGS att2 partials ----------------
__global__ __launch_bounds__(256) void k_scores(const float* __restrict__ att1,
                                                const float* __restrict__ agp,
                                                const float* __restrict__ wfull,
                                                float* __restrict__ scores) {
    int wid = threadIdx.x >> 6, lane = threadIdx.x & 63;
    int bn = blockIdx.x * 4 + wid;            // 12544 rows
    int b = bn / N;
    const float* a1 = att1 + (size_t)bn * AA;
    const float* a2 = agp + (size_t)b * AGW;
    const size_t SL = (size_t)B * AGW;
    float s = 0.f;
#pragma unroll
    for (int i = 0; i < AA / 256; ++i) {
        int a = i * 256 + lane * 4;
        float4 v  = *(const float4*)&a1[a];
        float4 p0 = *(const float4*)&a2[a];
        float4 p1 = *(const float4*)&a2[SL + a];
        float4 p2 = *(const float4*)&a2[2 * SL + a];
        float4 p3 = *(const float4*)&a2[3 * SL + a];
        float4 wf = *(const float4*)&wfull[a];
        s += fmaxf(v.x + p0.x + p1.x + p2.x + p3.x, 0.f) * wf.x;
        s += fmaxf(v.y + p0.y + p1.y + p2.y + p3.y, 0.f) * wf.y;
        s += fmaxf(v.z + p0.z + p1.z + p2.z + p3.z, 0.f) * wf.z;
        s += fmaxf(v.w + p0.w + p1.w + p2.w + p3.w, 0.f) * wf.w;
    }
    for (int off = 32; off; off >>= 1) s += __shfl_down(s, off);
    if (lane == 0) scores[bn] = s;
}

// ---------------- awe: in-block softmax + float4 weighted sum + gate ----------------
// grid (E/1024, B) = (2, 64); thread owns 4 consecutive e's.
__global__ __launch_bounds__(256) void k_awe(const float* __restrict__ scores,
                                             const float* __restrict__ feat,
                                             const float* __restrict__ agp,
                                             float* __restrict__ xcat) {
    __shared__ float al[N];
    __shared__ float red[256];
    int b = blockIdx.y, ch = blockIdx.x, t = threadIdx.x;
    float v = (t < N) ? scores[b * N + t] : -INFINITY;
    red[t] = v; __syncthreads();
    for (int s = 128; s; s >>= 1) { if (t < s) red[t] = fmaxf(red[t], red[t + s]); __syncthreads(); }
    float mx = red[0]; __syncthreads();
    float e = (t < N) ? expf(v - mx) : 0.f;
    red[t] = e; __syncthreads();
    for (int s = 128; s; s >>= 1) { if (t < s) red[t] += red[t + s]; __syncthreads(); }
    float inv = 1.0f / red[0];
    if (t < N) al[t] = e * inv;
    __syncthreads();
    int e0 = ch * 1024 + t * 4;
    const float* f = feat + (size_t)b * N * E + e0;
    float4 s4 = {0.f, 0.f, 0.f, 0.f};
    for (int n = 0; n < N; n += 2) {
        float a0 = al[n], a1v = al[n + 1];
        float4 f0 = *(const float4*)f;
        float4 f1 = *(const float4*)(f + E);
        s4.x += a0 * f0.x + a1v * f1.x;
        s4.y += a0 * f0.y + a1v * f1.y;
        s4.z += a0 * f0.z + a1v * f1.z;
        s4.w += a0 * f0.w + a1v * f1.w;
        f += (size_t)2 * E;
    }
    const float* gp = agp + (size_t)b * AGW + AA + e0;
    const size_t SL = (size_t)B * AGW;
    float4 g0 = *(const float4*)&gp[0];
    float4 g1 = *(const float4*)&gp[SL];
    float4 g2 = *(const float4*)&gp[2 * SL];
    float4 g3 = *(const float4*)&gp[3 * SL];
    float4 o;
    o.x = s4.x * sigmoidf_(g0.x + g1.x + g2.x + g3.x);
    o.y = s4.y * sigmoidf_(g0.y + g1.y + g2.y + g3.y);
    o.z = s4.z * sigmoidf_(g0.z + g1.z + g2.z + g3.z);
    o.w = s4.w * sigmoidf_(g0.w + g1.w + g2.w + g3.w);
    *(float4*)&xcat[(size_t)b * XC + EM + e0] = o;
}

// ---------------- z partials: one launch, 12 slices (8 ih + 4 hh), prefetched ----------------
__global__ __launch_bounds__(256) void k_z(const float* __restrict__ xcat,
                                           const float* __restrict__ Wih,
                                           const float* __restrict__ Whh,
                                           float* __restrict__ zpart) {
    __shared__ float As[16][68];
    __shared__ float Bs[16][64];
    int slice = blockIdx.y;
    const float* A; const float* W; int kbeg, kspan;
    if (slice < ZS1) { A = xcat;        W = Wih; kbeg = slice * ((EM + E) / ZS1); kspan = (EM + E) / ZS1; }
    else             { A = xcat + HOFF; W = Whh; kbeg = (slice - ZS1) * (D / ZS2); kspan = D / ZS2; }
    int kend = kbeg + kspan;
    float* C = zpart + (size_t)slice * B * 4 * D;
    int n0 = blockIdx.x * 64;
    int t = threadIdx.x;
    int tx = t & 15, ty = t >> 4;
    int arow = t >> 2, ak4 = (t & 3) * 4;
    int bk = t >> 4, bc4 = (t & 15) * 4;
    float4 pav = *(const float4*)&A[(size_t)arow * XC + kbeg + ak4];
    float4 pbv = *(const float4*)&W[(size_t)(kbeg + bk) * (4 * D) + n0 + bc4];
    float acc[4][4] = {};
    for (int k0 = kbeg; k0 < kend; k0 += 16) {
        As[ak4 + 0][arow] = pav.x; As[ak4 + 1][arow] = pav.y;
        As[ak4 + 2][arow] = pav.z; As[ak4 + 3][arow] = pav.w;
        *(float4*)&Bs[bk][bc4] = pbv;
        __syncthreads();
        if (k0 + 16 < kend) {
            pav = *(const float4*)&A[(size_t)arow * XC + k0 + 16 + ak4];
            pbv = *(const float4*)&W[(size_t)(k0 + 16 + bk) * (4 * D) + n0 + bc4];
        }
#pragma unroll
        for (int kk = 0; kk < 16; ++kk) {
            float4 a4 = *(const float4*)&As[kk][ty * 4];
            float4 b4 = *(const float4*)&Bs[kk][tx * 4];
            acc[0][0] += a4.x * b4.x; acc[0][1] += a4.x * b4.y; acc[0][2] += a4.x * b4.z; acc[0][3] += a4.x * b4.w;
            acc[1][0] += a4.y * b4.x; acc[1][1] += a4.y * b4.y; acc[1][2] += a4.y * b4.z; acc[1][3] += a4.y * b4.w;
            acc[2][0] += a4.z * b4.x; acc[2][1] += a4.z * b4.y; acc[2][2] += a4.z * b4.z; acc[2][3] += a4.z * b4.w;
            acc[3][0] += a4.w * b4.x; acc[3][1] += a4.w * b4.y; acc[3][2] += a4.w * b4.z; acc[3][3] += a4.w * b4.w;
        }
        __syncthreads();
    }
#pragma unroll
    for (int i = 0; i < 4; ++i) {
        int row = ty * 4 + i;
#pragma unroll
        for (int j = 0; j < 4; ++j)
            C[(size_t)row * (4 * D) + n0 + tx * 4 + j] = acc[i][j];
    }
}

// ---------------- LSTM float4: reduce 12 zpart slices + gates; h -> xcat ----------------
__global__ __launch_bounds__(256) void k_lstm(const float* __restrict__ zpart,
                                              const float* __restrict__ blstm,
                                              float* __restrict__ c,
                                              float* __restrict__ xcat) {
    int i4 = blockIdx.x * 256 + threadIdx.x;  // 8192 total (B*D/4)
    int b = i4 >> 7;
    int d4 = (i4 & 127) << 2;
    const float* zp = zpart + (size_t)b * (4 * D);
    float4 zi = *(const float4*)&blstm[d4];
    float4 zf = *(const float4*)&blstm[D + d4];
    float4 zg = *(const float4*)&blstm[2 * D + d4];
    float4 zo = *(const float4*)&blstm[3 * D + d4];
#pragma unroll
    for (int s = 0; s < ZS1 + ZS2; ++s) {
        const float* p = zp + (size_t)s * B * 4 * D;
        float4 a = *(const float4*)&p[d4];
        float4 bb = *(const float4*)&p[D + d4];
        float4 g = *(const float4*)&p[2 * D + d4];
        float4 o = *(const float4*)&p[3 * D + d4];
        zi.x += a.x; zi.y += a.y; zi.z += a.z; zi.w += a.w;
        zf.x += bb.x; zf.y += bb.y; zf.z += bb.z; zf.w += bb.w;
        zg.x += g.x; zg.y += g.y; zg.z += g.z; zg.w += g.w;
        zo.x += o.x; zo.y += o.y; zo.z += o.z; zo.w += o.w;
    }
    float4 cv = *(float4*)&c[(size_t)b * D + d4];
    float4 hv;
#define LSTM1(comp) { \
        float cn = sigmoidf_(zf.comp) * cv.comp + sigmoidf_(zi.comp) * tanhf(zg.comp); \
        cv.comp = cn; hv.comp = sigmoidf_(zo.comp) * tanhf(cn); }
    LSTM1(x) LSTM1(y) LSTM1(z) LSTM1(w)
#undef LSTM1
    *(float4*)&c[(size_t)b * D + d4] = cv;
    *(float4*)&xcat[(size_t)b * XC + HOFF + d4] = hv;
}

// ---------------- preds split-K: predsp[sl][b][V] (prefetched) ----------------
__global__ __launch_bounds__(256) void k_preds(const float* __restrict__ xcat,
                                               const float* __restrict__ Wfc,
                                               const float* __restrict__ bfc,
                                               float* __restrict__ predsp) {
    __shared__ float As[16][68];
    __shared__ float Bs[16][64];
    int slice = blockIdx.y;
    int kbeg = slice * (D / PS), kend = kbeg + D / PS;
    float* preds = predsp + (size_t)slice * B * V;
    const float* bias = (slice == 0) ? bfc : nullptr;
    const float* A = xcat + HOFF;
    int n0 = blockIdx.x * 64;
    int t = threadIdx.x;
    int tx = t & 15, ty = t >> 4;
    int arow = t >> 2, ak4 = (t & 3) * 4;
    int bk = t >> 4, bc4 = (t & 15) * 4;
    float4 pav = *(const float4*)&A[(size_t)arow * XC + kbeg + ak4];
    float4 pbv = ldg4_guard(&Wfc[(size_t)(kbeg + bk) * V], n0 + bc4, V);
    float acc[4][4] = {};
    for (int k0 = kbeg; k0 < kend; k0 += 16) {
        As[ak4 + 0][arow] = pav.x; As[ak4 + 1][arow] = pav.y;
        As[ak4 + 2][arow] = pav.z; As[ak4 + 3][arow] = pav.w;
        *(float4*)&Bs[bk][bc4] = pbv;
        __syncthreads();
        if (k0 + 16 < kend) {
            pav = *(const float4*)&A[(size_t)arow * XC + k0 + 16 + ak4];
            pbv = ldg4_guard(&Wfc[(size_t)(k0 + 16 + bk) * V], n0 + bc4, V);
        }
#pragma unroll
        for (int kk = 0; kk < 16; ++kk) {
            float4 a4 = *(const float4*)&As[kk][ty * 4];
            float4 b4 = *(const float4*)&Bs[kk][tx * 4];
            acc[0][0] += a4.x * b4.x; acc[0][1] += a4.x * b4.y; acc[0][2] += a4.x * b4.z; acc[0][3] += a4.x * b4.w;
            acc[1][0] += a4.y * b4.x; acc[1][1] += a4.y * b4.y; acc[1][2] += a4.y * b4.z; acc[1][3] += a4.y * b4.w;
            acc[2][0] += a4.z * b4.x; acc[2][1] += a4.z * b4.y; acc[2][2] += a4.z * b4.z; acc[2][3] += a4.z * b4.w;
            acc[3][0] += a4.w * b4.x; acc[3][1] += a4.w * b4.y; acc[3][2] += a4.w * b4.z; acc[3][3] += a4.w * b4.w;
        }
        __syncthreads();
    }
#pragma unroll
    for (int i = 0; i < 4; ++i) {
        int row = ty * 4 + i;
#pragma unroll
        for (int j = 0; j < 4; ++j) {
            int col = n0 + tx * 4 + j;
            if (col < V) {
                float v = acc[i][j];
                if (bias) v += bias[col];
                preds[(size_t)row * V + col] = v;
            }
        }
    }
}

// ---------------- argmax over V (sums PS partials) -> token + next inp ----------------
__global__ __launch_bounds__(256) void k_argmax(const float* __restrict__ predsp,
                                                const float* __restrict__ emb,
                                                float* __restrict__ xcat,
                                                int* __restrict__ out,
                                                int step) {
    __shared__ float vals[256];
    __shared__ int idxs[256];
    __shared__ int pid_sh;
    int b = blockIdx.x, t = threadIdx.x;
    const float* p0 = predsp + (size_t)b * V;
    const float* p1 = predsp + (size_t)B * V + (size_t)b * V;
    float best = -INFINITY; int bi = 0;
    for (int v = t; v < V; v += 256) {
        float pv = p0[v] + p1[v];
        if (pv > best) { best = pv; bi = v; }
    }
    vals[t] = best; idxs[t] = bi; __syncthreads();
    for (int s = 128; s; s >>= 1) {
        if (t < s) {
            float ov = vals[t + s]; int oi = idxs[t + s];
            if (ov > vals[t] || (ov == vals[t] && oi < idxs[t])) { vals[t] = ov; idxs[t] = oi; }
        }
        __syncthreads();
    }
    if (t == 0) { pid_sh = idxs[0]; out[b * TSTEPS + step] = idxs[0]; }
    __syncthreads();
    int pid = pid_sh;
    for (int k = t; k < EM; k += 256) xcat[(size_t)b * XC + k] = emb[(size_t)pid * EM + k];
}

extern "C" void kernel_launch(void* const* d_in, const int* in_sizes, int n_in,
                              void* d_out, int out_size, void* d_ws, size_t ws_size,
                              hipStream_t stream) {
    const float* feat   = (const float*)d_in[0];
    const float* emb    = (const float*)d_in[1];
    const float* Wea    = (const float*)d_in[2];
    const float* Wda    = (const float*)d_in[3];
    const float* wfull  = (const float*)d_in[4];
    const float* Wih_   = (const float*)d_in[5];
    const float* bih    = (const float*)d_in[6];
    const float* Wic    = (const float*)d_in[7];
    const float* bic    = (const float*)d_in[8];
    const float* Wfb    = (const float*)d_in[9];
    const float* bfb    = (const float*)d_in[10];
    const float* Wih    = (const float*)d_in[11];
    const float* Whh    = (const float*)d_in[12];
    const float* blstm  = (const float*)d_in[13];
    const float* Wfc    = (const float*)d_in[14];
    const float* bfc    = (const float*)d_in[15];
    int* out = (int*)d_out;

    float* ws = (float*)d_ws;
    float* att1     = ws;                              // 2 x 6,422,528 (slice1 follows slice0)
    float* mean_enc = att1 + 2 * ATT1_ELEMS;           // 131,072
    float* c        = mean_enc + (size_t)B * E;        // 32,768
    float* agp      = c + (size_t)B * D;               // 655,360
    float* scores   = agp + (size_t)AGS * B * AGW;     // 12,544
    float* xcat     = scores + (size_t)B * N;          // 196,608
    float* zpart    = xcat + (size_t)B * XC;           // 1,572,864
    float* predsp   = zpart + (size_t)(ZS1 + ZS2) * B * 4 * D;  // 1,280,000
    // total ~67 MB

    // ---- one-time (per call) ----
    k_mean<<<(B * E) / 256, 256, 0, stream>>>(feat, mean_enc);
    k_init_hc<<<(B * D) / 256, 256, 0, stream>>>(mean_enc, Wih_, bih, Wic, bic, xcat, c);
    k_init_inp<<<(B * EM) / 256, 256, 0, stream>>>(emb, xcat);
    k_gemm_att1<<<dim3((B * N / 256) * (AA / 128), 2), 256, 0, stream>>>(feat, Wea, att1);
    k_att1_red<<<ATT1_ELEMS / 1024, 256, 0, stream>>>(att1);

    for (int t = 0; t < TSTEPS; ++t) {
        k_ag<<<dim3(40, AGS), 256, 0, stream>>>(xcat, Wda, Wfb, bfb, agp);
        k_scores<<<(B * N) / 4, 256, 0, stream>>>(att1, agp, wfull, scores);
        k_awe<<<dim3(E / 1024, B), 256, 0, stream>>>(scores, feat, agp, xcat);
        k_z<<<dim3((4 * D) / 64, ZS1 + ZS2), 256, 0, stream>>>(xcat, Wih, Whh, zpart);
        k_lstm<<<(B * D / 4) / 256, 256, 0, stream>>>(zpart, blstm, c, xcat);
        k_preds<<<dim3((V + 63) / 64, PS), 256, 0, stream>>>(xcat, Wfc, bfc, predsp);
        k_argmax<<<B, 256, 0, stream>>>(predsp, emb, xcat, out, t);
    }
}

// Round 9
// 2277.943 us; speedup vs baseline: 1.0086x; 1.0086x over previous
//
#include <hip/hip_runtime.h>
#include <math.h>

#define B 64
#define N 196
#define E 2048
#define D 512
#define AA 512
#define EM 512
#define V 10000
#define TSTEPS 20
#define XC 3072          // xcat: [inp(512) | awe(2048) | h(512)] contiguous
#define HOFF 2560        // h slot offset in xcat
#define AGW 2560         // ag row: [att2(512) | gate(2048)]
#define AGS 4            // split-K slices for att2|gate (K=512 -> 128 each)
#define ZS1 8            // split-K slices for W_ih (K=2560 -> 320 each)
#define ZS2 4            // split-K slices for W_hh (K=512 -> 128 each)
#define PS 2             // split-K slices for preds (K=512 -> 256 each)
#define ATT1_ELEMS ((size_t)B * N * AA)   // 6422528

__device__ __forceinline__ float sigmoidf_(float x) { return 1.0f / (1.0f + expf(-x)); }

__device__ __forceinline__ float4 ldg4_guard(const float* __restrict__ wp, int n, int Nn) {
    if (n + 3 < Nn) return *(const float4*)&wp[n];
    float4 bv;
    bv.x = (n     < Nn) ? wp[n]     : 0.f;
    bv.y = (n + 1 < Nn) ? wp[n + 1] : 0.f;
    bv.z = (n + 2 < Nn) ? wp[n + 2] : 0.f;
    bv.w = (n + 3 < Nn) ? wp[n + 3] : 0.f;
    return bv;
}

// ---------------- mean over N ----------------
__global__ __launch_bounds__(256) void k_mean(const float* __restrict__ feat,
                                              float* __restrict__ mean_enc) {
    int i = blockIdx.x * 256 + threadIdx.x;
    int b = i >> 11, e = i & (E - 1);
    const float* p = feat + (size_t)b * N * E + e;
    float s = 0.f;
    for (int n = 0; n < N; ++n) s += p[(size_t)n * E];
    mean_enc[i] = s * (1.0f / (float)N);
}

// ---------------- h,c init; h written into xcat h-slot ----------------
__global__ __launch_bounds__(256) void k_init_hc(const float* __restrict__ me,
                                                 const float* __restrict__ Wh, const float* __restrict__ bh,
                                                 const float* __restrict__ Wc, const float* __restrict__ bc,
                                                 float* __restrict__ xcat, float* __restrict__ c) {
    int i = blockIdx.x * 256 + threadIdx.x;
    int b = i >> 9, d = i & (D - 1);
    const float* m = me + (size_t)b * E;
    float ha = bh[d], ca = bc[d];
    for (int e = 0; e < E; ++e) {
        float mv = m[e];
        ha += mv * Wh[(size_t)e * D + d];
        ca += mv * Wc[(size_t)e * D + d];
    }
    xcat[(size_t)b * XC + HOFF + d] = ha;
    c[i] = ca;
}

// ---------------- inp = embedding[1] into xcat ----------------
__global__ __launch_bounds__(256) void k_init_inp(const float* __restrict__ emb,
                                                  float* __restrict__ xcat) {
    int i = blockIdx.x * 256 + threadIdx.x;   // 32768
    int b = i >> 9, k = i & (EM - 1);
    xcat[(size_t)b * XC + k] = emb[EM + k];
}

// ---------------- att1 = enc @ W_enc_att : 256x128 tile, 16x8 micro, split-K 2 ----------------
// Bank-conflict-free layout: B-fragment cols = {tx*4+j} u {64+tx*4+j} -> every LDS read AND
// staging write spans 256 B contiguous per 16-lane group = 2 addr/bank (free, m136).
// A staged [k][m] via scalar column writes (64-lane contiguous, clean); A-frag reads 2-way broadcast.
__global__ __launch_bounds__(256) void k_gemm_att1(const float* __restrict__ Am,
                                                   const float* __restrict__ Bm,
                                                   float* __restrict__ Cp) {
    __shared__ float As[16][256];   // [k][m]
    __shared__ float Bs[16][128];   // [k][n]
    int bid = blockIdx.x;           // 196 = 49 row-tiles x 4 col-tiles
    int xcd = bid & 7, idx = bid >> 3;
    int wg = (xcd < 4 ? xcd * 25 : 100 + (xcd - 4) * 24) + idx;   // bijective (m204)
    int row0 = (wg >> 2) * 256, col0 = (wg & 3) * 128;
    int kbeg = blockIdx.y * (E / 2);
    float* Cm = Cp + (size_t)blockIdx.y * ATT1_ELEMS;
    int t = threadIdx.x;
    int ty = t >> 4, tx = t & 15;
    int brow = t >> 4, bc = (t & 15) * 4;                    // B staging coords
    const float* aptr = Am + (size_t)(row0 + t) * E + kbeg;  // 1 A-row per thread
    const float* bptr = Bm + (size_t)(kbeg + brow) * AA + col0;
    float4 pa0 = *(const float4*)(aptr);
    float4 pa1 = *(const float4*)(aptr + 4);
    float4 pa2 = *(const float4*)(aptr + 8);
    float4 pa3 = *(const float4*)(aptr + 12);
    float4 pb0 = *(const float4*)(bptr + bc);
    float4 pb1 = *(const float4*)(bptr + 64 + bc);
    float acc[16][8] = {};
    for (int k0 = 0; k0 < E / 2; k0 += 16) {
        As[ 0][t] = pa0.x; As[ 1][t] = pa0.y; As[ 2][t] = pa0.z; As[ 3][t] = pa0.w;
        As[ 4][t] = pa1.x; As[ 5][t] = pa1.y; As[ 6][t] = pa1.z; As[ 7][t] = pa1.w;
        As[ 8][t] = pa2.x; As[ 9][t] = pa2.y; As[10][t] = pa2.z; As[11][t] = pa2.w;
        As[12][t] = pa3.x; As[13][t] = pa3.y; As[14][t] = pa3.z; As[15][t] = pa3.w;
        *(float4*)&Bs[brow][bc]      = pb0;
        *(float4*)&Bs[brow][64 + bc] = pb1;
        __syncthreads();
        if (k0 + 16 < E / 2) {      // prefetch next k-tile (in flight during compute)
            const float* ap = aptr + k0 + 16;
            const float* bp = bptr + (size_t)(k0 + 16) * AA;
            pa0 = *(const float4*)(ap);
            pa1 = *(const float4*)(ap + 4);
            pa2 = *(const float4*)(ap + 8);
            pa3 = *(const float4*)(ap + 12);
            pb0 = *(const float4*)(bp + bc);
            pb1 = *(const float4*)(bp + 64 + bc);
        }
#pragma unroll
        for (int kk = 0; kk < 16; ++kk) {
            float af[16], bf[8];
            *(float4*)&af[0]  = *(const float4*)&As[kk][ty * 16];
            *(float4*)&af[4]  = *(const float4*)&As[kk][ty * 16 + 4];
            *(float4*)&af[8]  = *(const float4*)&As[kk][ty * 16 + 8];
            *(float4*)&af[12] = *(const float4*)&As[kk][ty * 16 + 12];
            *(float4*)&bf[0]  = *(const float4*)&Bs[kk][tx * 4];
            *(float4*)&bf[4]  = *(const float4*)&Bs[kk][64 + tx * 4];
#pragma unroll
            for (int i = 0; i < 16; ++i)
#pragma unroll
                for (int j = 0; j < 8; ++j)
                    acc[i][j] += af[i] * bf[j];
        }
        __syncthreads();
    }
#pragma unroll
    for (int i = 0; i < 16; ++i) {
        float* cp = &Cm[(size_t)(row0 + ty * 16 + i) * AA + col0];
        float4 lo, hi;
        lo.x = acc[i][0]; lo.y = acc[i][1]; lo.z = acc[i][2]; lo.w = acc[i][3];
        hi.x = acc[i][4]; hi.y = acc[i][5]; hi.z = acc[i][6]; hi.w = acc[i][7];
        *(float4*)(cp + tx * 4)      = lo;
        *(float4*)(cp + 64 + tx * 4) = hi;
    }
}

// ---------------- att1 += att1 slice1 (in place, deterministic) ----------------
__global__ __launch_bounds__(256) void k_att1_red(float* __restrict__ att1) {
    size_t i = ((size_t)blockIdx.x * 256 + threadIdx.x) * 4;
    float4 a = *(float4*)&att1[i];
    float4 b = *(const float4*)&att1[i + ATT1_ELEMS];
    a.x += b.x; a.y += b.y; a.z += b.z; a.w += b.w;
    *(float4*)&att1[i] = a;
}

// ---------------- att2|gate split-K: agp[sl][b][2560] (register-prefetched) ----------------
__global__ __launch_bounds__(256) void k_ag(const float* __restrict__ xcat,
                                            const float* __restrict__ Wda,
                                            const float* __restrict__ Wfb,
                                            const float* __restrict__ bfb,
                                            float* __restrict__ agp) {
    __shared__ float As[16][68];
    __shared__ float Bs[16][64];
    int tile = blockIdx.x, slice = blockIdx.y;
    const float* W; const float* bias = nullptr; int ldw, n0, co;
    if (tile < 8) { W = Wda; ldw = AA; n0 = tile * 64;       co = n0; }
    else          { W = Wfb; ldw = E;  n0 = (tile - 8) * 64; co = AA + n0;
                    if (slice == 0) bias = bfb; }
    float* ag = agp + (size_t)slice * B * AGW;
    int kbeg = slice * (D / AGS), kend = kbeg + D / AGS;
    const float* A = xcat + HOFF;
    int t = threadIdx.x;
    int tx = t & 15, ty = t >> 4;
    int arow = t >> 2, ak4 = (t & 3) * 4;
    int bk = t >> 4, bc4 = (t & 15) * 4;
    float4 pav = *(const float4*)&A[(size_t)arow * XC + kbeg + ak4];
    float4 pbv = *(const float4*)&W[(size_t)(kbeg + bk) * ldw + n0 + bc4];
    float acc[4][4] = {};
    for (int k0 = kbeg; k0 < kend; k0 += 16) {
        As[ak4 + 0][arow] = pav.x; As[ak4 + 1][arow] = pav.y;
        As[ak4 + 2][arow] = pav.z; As[ak4 + 3][arow] = pav.w;
        *(float4*)&Bs[bk][bc4] = pbv;
        __syncthreads();
        if (k0 + 16 < kend) {
            pav = *(const float4*)&A[(size_t)arow * XC + k0 + 16 + ak4];
            pbv = *(const float4*)&W[(size_t)(k0 + 16 + bk) * ldw + n0 + bc4];
        }
#pragma unroll
        for (int kk = 0; kk < 16; ++kk) {
            float4 a4 = *(const float4*)&As[kk][ty * 4];
            float4 b4 = *(const float4*)&Bs[kk][tx * 4];
            acc[0][0] += a4.x * b4.x; acc[0][1] += a4.x * b4.y; acc[0][2] += a4.x * b4.z; acc[0][3] += a4.x * b4.w;
            acc[1][0] += a4.y * b4.x; acc[1][1] += a4.y * b4.y; acc[1][2] += a4.y * b4.z; acc[1][3] += a4.y * b4.w;
            acc[2][0] += a4.z * b4.x; acc[2][1] += a4.z * b4.y; acc[2][2] += a4.z * b4.z; acc[2][3] += a4.z * b4.w;
            acc[3][0] += a4.w * b4.x; acc[3][1] += a4.w * b4.y; acc[3][2] += a4.w * b4.z; acc[3][3] += a4.w * b4.w;
        }
        __syncthreads();
    }
#pragma unroll
    for (int i = 0; i < 4; ++i) {
        int row = ty * 4 + i;
#pragma unroll
        for (int j = 0; j < 4; ++j) {
            float v = acc[i][j];
            if (bias) v += bias[n0 + tx * 4 + j];
            ag[(size_t)row * AGW + co + tx * 4 + j] = v;
        }
    }
}

// ---------------- scores: wave per (b,n) row, float4; sums AGS att2 partials ----------------
__global__ __launch_bounds__(256) void k_scores(const float* __restrict__ att1,
                                                const float* __restrict__ agp,
                                                const float* __restrict__ wfull,
                                                float* __restrict__ scores) {
    int wid = threadIdx.x >> 6, lane = threadIdx.x & 63;
    int bn = blockIdx.x * 4 + wid;            // 12544 rows
    int b = bn / N;
    const float* a1 = att1 + (size_t)bn * AA;
    const float* a2 = agp + (size_t)b * AGW;
    const size_t SL = (size_t)B * AGW;
    float s = 0.f;
#pragma unroll
    for (int i = 0; i < AA / 256; ++i) {
        int a = i * 256 + lane * 4;
        float4 v  = *(const float4*)&a1[a];
        float4 p0 = *(const float4*)&a2[a];
        float4 p1 = *(const float4*)&a2[SL + a];
        float4 p2 = *(const float4*)&a2[2 * SL + a];
        float4 p3 = *(const float4*)&a2[3 * SL + a];
        float4 wf = *(const float4*)&wfull[a];
        s += fmaxf(v.x + p0.x + p1.x + p2.x + p3.x, 0.f) * wf.x;
        s += fmaxf(v.y + p0.y + p1.y + p2.y + p3.y, 0.f) * wf.y;
        s += fmaxf(v.z + p0.z + p1.z + p2.z + p3.z, 0.f) * wf.z;
        s += fmaxf(v.w + p0.w + p1.w + p2.w + p3.w, 0.f) * wf.w;
    }
    for (int off = 32; off; off >>= 1) s += __shfl_down(s, off);
    if (lane == 0) scores[bn] = s;
}

// ---------------- awe: in-block softmax + float2 weighted sum + gate ----------------
// grid (E/512, B) = (4, 64) = 256 blocks; thread owns 2 consecutive e's.
// N=196 is even: the n-loop covers all rows exactly (NO tail — r8 crash was an OOB tail read).
__global__ __launch_bounds__(256) void k_awe(const float* __restrict__ scores,
                                             const float* __restrict__ feat,
                                             const float* __restrict__ agp,
                                             float* __restrict__ xcat) {
    __shared__ float al[N];
    __shared__ float red[256];
    int b = blockIdx.y, ch = blockIdx.x, t = threadIdx.x;
    float v = (t < N) ? scores[b * N + t] : -INFINITY;
    red[t] = v; __syncthreads();
    for (int s = 128; s; s >>= 1) { if (t < s) red[t] = fmaxf(red[t], red[t + s]); __syncthreads(); }
    float mx = red[0]; __syncthreads();
    float e = (t < N) ? expf(v - mx) : 0.f;
    red[t] = e; __syncthreads();
    for (int s = 128; s; s >>= 1) { if (t < s) red[t] += red[t + s]; __syncthreads(); }
    float inv = 1.0f / red[0];
    if (t < N) al[t] = e * inv;
    __syncthreads();
    int e0 = ch * 512 + t * 2;
    const float* f = feat + (size_t)b * N * E + e0;
    float sx = 0.f, sy = 0.f;
    for (int n = 0; n < N; n += 2) {
        float a0 = al[n], a1v = al[n + 1];
        float2 f0 = *(const float2*)f;
        float2 f1 = *(const float2*)(f + E);
        sx += a0 * f0.x + a1v * f1.x;
        sy += a0 * f0.y + a1v * f1.y;
        f += (size_t)2 * E;
    }
    const float* gp = agp + (size_t)b * AGW + AA + e0;
    const size_t SL = (size_t)B * AGW;
    float2 g0 = *(const float2*)&gp[0];
    float2 g1 = *(const float2*)&gp[SL];
    float2 g2 = *(const float2*)&gp[2 * SL];
    float2 g3 = *(const float2*)&gp[3 * SL];
    float2 o;
    o.x = sx * sigmoidf_(g0.x + g1.x + g2.x + g3.x);
    o.y = sy * sigmoidf_(g0.y + g1.y + g2.y + g3.y);
    *(float2*)&xcat[(size_t)b * XC + EM + e0] = o;
}

// ---------------- z partials: one launch, 12 slices (8 ih + 4 hh), prefetched ----------------
__global__ __launch_bounds__(256) void k_z(const float* __restrict__ xcat,
                                           const float* __restrict__ Wih,
                                           const float* __restrict__ Whh,
                                           float* __restrict__ zpart) {
    __shared__ float As[16][68];
    __shared__ float Bs[16][64];
    int slice = blockIdx.y;
    const float* A; const float* W; int kbeg, kspan;
    if (slice < ZS1) { A = xcat;        W = Wih; kbeg = slice * ((EM + E) / ZS1); kspan = (EM + E) / ZS1; }
    else             { A = xcat + HOFF; W = Whh; kbeg = (slice - ZS1) * (D / ZS2); kspan = D / ZS2; }
    int kend = kbeg + kspan;
    float* C = zpart + (size_t)slice * B * 4 * D;
    int n0 = blockIdx.x * 64;
    int t = threadIdx.x;
    int tx = t & 15, ty = t >> 4;
    int arow = t >> 2, ak4 = (t & 3) * 4;
    int bk = t >> 4, bc4 = (t & 15) * 4;
    float4 pav = *(const float4*)&A[(size_t)arow * XC + kbeg + ak4];
    float4 pbv = *(const float4*)&W[(size_t)(kbeg + bk) * (4 * D) + n0 + bc4];
    float acc[4][4] = {};
    for (int k0 = kbeg; k0 < kend; k0 += 16) {
        As[ak4 + 0][arow] = pav.x; As[ak4 + 1][arow] = pav.y;
        As[ak4 + 2][arow] = pav.z; As[ak4 + 3][arow] = pav.w;
        *(float4*)&Bs[bk][bc4] = pbv;
        __syncthreads();
        if (k0 + 16 < kend) {
            pav = *(const float4*)&A[(size_t)arow * XC + k0 + 16 + ak4];
            pbv = *(const float4*)&W[(size_t)(k0 + 16 + bk) * (4 * D) + n0 + bc4];
        }
#pragma unroll
        for (int kk = 0; kk < 16; ++kk) {
            float4 a4 = *(const float4*)&As[kk][ty * 4];
            float4 b4 = *(const float4*)&Bs[kk][tx * 4];
            acc[0][0] += a4.x * b4.x; acc[0][1] += a4.x * b4.y; acc[0][2] += a4.x * b4.z; acc[0][3] += a4.x * b4.w;
            acc[1][0] += a4.y * b4.x; acc[1][1] += a4.y * b4.y; acc[1][2] += a4.y * b4.z; acc[1][3] += a4.y * b4.w;
            acc[2][0] += a4.z * b4.x; acc[2][1] += a4.z * b4.y; acc[2][2] += a4.z * b4.z; acc[2][3] += a4.z * b4.w;
            acc[3][0] += a4.w * b4.x; acc[3][1] += a4.w * b4.y; acc[3][2] += a4.w * b4.z; acc[3][3] += a4.w * b4.w;
        }
        __syncthreads();
    }
#pragma unroll
    for (int i = 0; i < 4; ++i) {
        int row = ty * 4 + i;
#pragma unroll
        for (int j = 0; j < 4; ++j)
            C[(size_t)row * (4 * D) + n0 + tx * 4 + j] = acc[i][j];
    }
}

// ---------------- LSTM float4: reduce 12 zpart slices + gates; h -> xcat ----------------
__global__ __launch_bounds__(256) void k_lstm(const float* __restrict__ zpart,
                                              const float* __restrict__ blstm,
                                              float* __restrict__ c,
                                              float* __restrict__ xcat) {
    int i4 = blockIdx.x * 256 + threadIdx.x;  // 8192 total (B*D/4)
    int b = i4 >> 7;
    int d4 = (i4 & 127) << 2;
    const float* zp = zpart + (size_t)b * (4 * D);
    float4 zi = *(const float4*)&blstm[d4];
    float4 zf = *(const float4*)&blstm[D + d4];
    float4 zg = *(const float4*)&blstm[2 * D + d4];
    float4 zo = *(const float4*)&blstm[3 * D + d4];
#pragma unroll
    for (int s = 0; s < ZS1 + ZS2; ++s) {
        const float* p = zp + (size_t)s * B * 4 * D;
        float4 a = *(const float4*)&p[d4];
        float4 bb = *(const float4*)&p[D + d4];
        float4 g = *(const float4*)&p[2 * D + d4];
        float4 o = *(const float4*)&p[3 * D + d4];
        zi.x += a.x; zi.y += a.y; zi.z += a.z; zi.w += a.w;
        zf.x += bb.x; zf.y += bb.y; zf.z += bb.z; zf.w += bb.w;
        zg.x += g.x; zg.y += g.y; zg.z += g.z; zg.w += g.w;
        zo.x += o.x; zo.y += o.y; zo.z += o.z; zo.w += o.w;
    }
    float4 cv = *(float4*)&c[(size_t)b * D + d4];
    float4 hv;
#define LSTM1(comp) { \
        float cn = sigmoidf_(zf.comp) * cv.comp + sigmoidf_(zi.comp) * tanhf(zg.comp); \
        cv.comp = cn; hv.comp = sigmoidf_(zo.comp) * tanhf(cn); }
    LSTM1(x) LSTM1(y) LSTM1(z) LSTM1(w)
#undef LSTM1
    *(float4*)&c[(size_t)b * D + d4] = cv;
    *(float4*)&xcat[(size_t)b * XC + HOFF + d4] = hv;
}

// ---------------- preds split-K: predsp[sl][b][V] (prefetched) ----------------
__global__ __launch_bounds__(256) void k_preds(const float* __restrict__ xcat,
                                               const float* __restrict__ Wfc,
                                               const float* __restrict__ bfc,
                                               float* __restrict__ predsp) {
    __shared__ float As[16][68];
    __shared__ float Bs[16][64];
    int slice = blockIdx.y;
    int kbeg = slice * (D / PS), kend = kbeg + D / PS;
    float* preds = predsp + (size_t)slice * B * V;
    const float* bias = (slice == 0) ? bfc : nullptr;
    const float* A = xcat + HOFF;
    int n0 = blockIdx.x * 64;
    int t = threadIdx.x;
    int tx = t & 15, ty = t >> 4;
    int arow = t >> 2, ak4 = (t & 3) * 4;
    int bk = t >> 4, bc4 = (t & 15) * 4;
    float4 pav = *(const float4*)&A[(size_t)arow * XC + kbeg + ak4];
    float4 pbv = ldg4_guard(&Wfc[(size_t)(kbeg + bk) * V], n0 + bc4, V);
    float acc[4][4] = {};
    for (int k0 = kbeg; k0 < kend; k0 += 16) {
        As[ak4 + 0][arow] = pav.x; As[ak4 + 1][arow] = pav.y;
        As[ak4 + 2][arow] = pav.z; As[ak4 + 3][arow] = pav.w;
        *(float4*)&Bs[bk][bc4] = pbv;
        __syncthreads();
        if (k0 + 16 < kend) {
            pav = *(const float4*)&A[(size_t)arow * XC + k0 + 16 + ak4];
            pbv = ldg4_guard(&Wfc[(size_t)(k0 + 16 + bk) * V], n0 + bc4, V);
        }
#pragma unroll
        for (int kk = 0; kk < 16; ++kk) {
            float4 a4 = *(const float4*)&As[kk][ty * 4];
            float4 b4 = *(const float4*)&Bs[kk][tx * 4];
            acc[0][0] += a4.x * b4.x; acc[0][1] += a4.x * b4.y; acc[0][2] += a4.x * b4.z; acc[0][3] += a4.x * b4.w;
            acc[1][0] += a4.y * b4.x; acc[1][1] += a4.y * b4.y; acc[1][2] += a4.y * b4.z; acc[1][3] += a4.y * b4.w;
            acc[2][0] += a4.z * b4.x; acc[2][1] += a4.z * b4.y; acc[2][2] += a4.z * b4.z; acc[2][3] += a4.z * b4.w;
            acc[3][0] += a4.w * b4.x; acc[3][1] += a4.w * b4.y; acc[3][2] += a4.w * b4.z; acc[3][3] += a4.w * b4.w;
        }
        __syncthreads();
    }
#pragma unroll
    for (int i = 0; i < 4; ++i) {
        int row = ty * 4 + i;
#pragma unroll
        for (int j = 0; j < 4; ++j) {
            int col = n0 + tx * 4 + j;
            if (col < V) {
                float v = acc[i][j];
                if (bias) v += bias[col];
                preds[(size_t)row * V + col] = v;
            }
        }
    }
}

// ---------------- argmax over V (sums PS partials) -> token + next inp ----------------
__global__ __launch_bounds__(256) void k_argmax(const float* __restrict__ predsp,
                                                const float* __restrict__ emb,
                                                float* __restrict__ xcat,
                                                int* __restrict__ out,
                                                int step) {
    __shared__ float vals[256];
    __shared__ int idxs[256];
    __shared__ int pid_sh;
    int b = blockIdx.x, t = threadIdx.x;
    const float* p0 = predsp + (size_t)b * V;
    const float* p1 = predsp + (size_t)B * V + (size_t)b * V;
    float best = -INFINITY; int bi = 0;
    for (int v = t; v < V; v += 256) {
        float pv = p0[v] + p1[v];
        if (pv > best) { best = pv; bi = v; }
    }
    vals[t] = best; idxs[t] = bi; __syncthreads();
    for (int s = 128; s; s >>= 1) {
        if (t < s) {
            float ov = vals[t + s]; int oi = idxs[t + s];
            if (ov > vals[t] || (ov == vals[t] && oi < idxs[t])) { vals[t] = ov; idxs[t] = oi; }
        }
        __syncthreads();
    }
    if (t == 0) { pid_sh = idxs[0]; out[b * TSTEPS + step] = idxs[0]; }
    __syncthreads();
    int pid = pid_sh;
    for (int k = t; k < EM; k += 256) xcat[(size_t)b * XC + k] = emb[(size_t)pid * EM + k];
}

extern "C" void kernel_launch(void* const* d_in, const int* in_sizes, int n_in,
                              void* d_out, int out_size, void* d_ws, size_t ws_size,
                              hipStream_t stream) {
    const float* feat   = (const float*)d_in[0];
    const float* emb    = (const float*)d_in[1];
    const float* Wea    = (const float*)d_in[2];
    const float* Wda    = (const float*)d_in[3];
    const float* wfull  = (const float*)d_in[4];
    const float* Wih_   = (const float*)d_in[5];
    const float* bih    = (const float*)d_in[6];
    const float* Wic    = (const float*)d_in[7];
    const float* bic    = (const float*)d_in[8];
    const float* Wfb    = (const float*)d_in[9];
    const float* bfb    = (const float*)d_in[10];
    const float* Wih    = (const float*)d_in[11];
    const float* Whh    = (const float*)d_in[12];
    const float* blstm  = (const float*)d_in[13];
    const float* Wfc    = (const float*)d_in[14];
    const float* bfc    = (const float*)d_in[15];
    int* out = (int*)d_out;

    float* ws = (float*)d_ws;
    float* att1     = ws;                              // 2 x 6,422,528 (slice1 follows slice0)
    float* mean_enc = att1 + 2 * ATT1_ELEMS;           // 131,072
    float* c        = mean_enc + (size_t)B * E;        // 32,768
    float* agp      = c + (size_t)B * D;               // 655,360
    float* scores   = agp + (size_t)AGS * B * AGW;     // 12,544
    float* xcat     = scores + (size_t)B * N;          // 196,608
    float* zpart    = xcat + (size_t)B * XC;           // 1,572,864
    float* predsp   = zpart + (size_t)(ZS1 + ZS2) * B * 4 * D;  // 1,280,000
    // total ~67 MB

    // ---- one-time (per call) ----
    k_mean<<<(B * E) / 256, 256, 0, stream>>>(feat, mean_enc);
    k_init_hc<<<(B * D) / 256, 256, 0, stream>>>(mean_enc, Wih_, bih, Wic, bic, xcat, c);
    k_init_inp<<<(B * EM) / 256, 256, 0, stream>>>(emb, xcat);
    k_gemm_att1<<<dim3((B * N / 256) * (AA / 128), 2), 256, 0, stream>>>(feat, Wea, att1);
    k_att1_red<<<ATT1_ELEMS / 1024, 256, 0, stream>>>(att1);

    for (int t = 0; t < TSTEPS; ++t) {
        k_ag<<<dim3(40, AGS), 256, 0, stream>>>(xcat, Wda, Wfb, bfb, agp);
        k_scores<<<(B * N) / 4, 256, 0, stream>>>(att1, agp, wfull, scores);
        k_awe<<<dim3(E / 512, B), 256, 0, stream>>>(scores, feat, agp, xcat);
        k_z<<<dim3((4 * D) / 64, ZS1 + ZS2), 256, 0, stream>>>(xcat, Wih, Whh, zpart);
        k_lstm<<<(B * D / 4) / 256, 256, 0, stream>>>(zpart, blstm, c, xcat);
        k_preds<<<dim3((V + 63) / 64, PS), 256, 0, stream>>>(xcat, Wfc, bfc, predsp);
        k_argmax<<<B, 256, 0, stream>>>(predsp, emb, xcat, out, t);
    }
}